// Round 21
// baseline (306.789 us; speedup 1.0000x reference)
//
#include <hip/hip_runtime.h>
#include <math.h>
#include <float.h>

// DeepSeek V3 router, round 21 = R13/R20 (best, reproduced 162us) + fused
// routing epilogue (last-block-reduces): the gemm's ~34us of non-gemm tail
// (route kernel launch + 33MB P re-read) is folded into the gemm. Each
// mb-group's last-arriving block (device-scope atomicAdd counter, no
// spinning -> no deadlock) routes its 64 rows reading P slices in FIXED ksl
// order -> bit-identical to the separate route kernel. Counters zeroed per
// call via hipMemsetAsync (graph-capture-legal).
// GEMM: 4-phase-per-K64 schedule, block 64Mx256N, 4 waves, wave-tile 64x64,
// A via XOR-swizzled LDS (2-deep X staging), B global->reg fragment-packed
// L2-resident planes, splitK=4, grid 512.
// Numerics (validated R7-R20): pass1 a0*b0; b0*=S5; a1*=S6; pass2 a1*b0s;
// a0*=S5; pass3 a0s*b3; a0=fp16(x), a1=fp16(res_x*2048), b0=fp16(256w),
// b3=fp16(res_w256*32); logit = acc/256.

#define TDIM 8192
#define DDIM 7168
#define EDIM 256
#define KT   (DDIM / 32)   // 224 k-tiles of 32
#define SPLITK 4

typedef _Float16 h8 __attribute__((ext_vector_type(8)));
typedef float  f16v __attribute__((ext_vector_type(16)));

// ---------------- K1: W -> 32x32x16-fragment-packed fp16 planes ------------
__global__ __launch_bounds__(256)
void convert_w(const float* __restrict__ W, _Float16* __restrict__ Bp)
{
    __shared__ _Float16 l0[64][80];
    __shared__ _Float16 l1[64][80];
    const int t = threadIdx.x;
    const int kt = blockIdx.x * 64;
    const int et = blockIdx.y * 64;
#pragma unroll
    for (int i = 0; i < 16; ++i) {
        const int kr = (t >> 6) * 16 + i;
        const int ec = t & 63;
        const float w = W[(size_t)(kt + kr) * EDIM + et + ec] * 256.f;
        const _Float16 h0 = (_Float16)w;
        const _Float16 h1 = (_Float16)((w - (float)h0) * 32.f);
        l0[ec][kr] = h0;
        l1[ec][kr] = h1;
    }
    __syncthreads();
#pragma unroll
    for (int j = 0; j < 2; ++j) {
        const int er = t >> 2;
        const int kc = ((t & 3) + 4 * j) * 8;
        const int e  = et + er;
        const int k  = kt + kc;
        const int cf   = e >> 5;
        const int lane = (e & 31) + 32 * ((k >> 3) & 1);
        const int kf   = (k >> 4) & 1;
        const int ktl  = k >> 5;
        const uint4 v0 = *(const uint4*)&l0[er][kc];
        const uint4 v1 = *(const uint4*)&l1[er][kc];
        const size_t o0 = (((size_t)(0 * 8 + cf) * KT + ktl) * 2 + kf) * 512 + lane * 8;
        const size_t o1 = (((size_t)(1 * 8 + cf) * KT + ktl) * 2 + kf) * 512 + lane * 8;
        *(uint4*)&Bp[o0] = v0;
        *(uint4*)&Bp[o1] = v1;
    }
}

// ---- K2: 4-phase-per-K64 split-fp16 GEMM + fused last-block routing -------
__global__ __launch_bounds__(256, 2)
void gemm_mfma(const float* __restrict__ X,
               const _Float16* __restrict__ Bp,
               float* __restrict__ P,
               const float* __restrict__ Bias,
               float* __restrict__ out,
               int* __restrict__ cnt)
{
    __shared__ _Float16 sA[2][2][64][64];   // [buf][plane][row][halfs], 64 KB
    __shared__ int isLast;

    const int t    = threadIdx.x;
    const int lane = t & 63;
    const int w    = t >> 6;                // wave -> n-quadrant w*64

    const int bid  = blockIdx.x;
    const int ks   = (bid & 7) % SPLITK;
    const int mb   = (bid >> 3) * (8 / SPLITK) + (bid & 7) / SPLITK;
    const int m0   = mb * 64;
    const int kLen = DDIM / SPLITK;
    const int kbeg = ks * kLen;
    const int nsteps = kLen >> 6;           // 28 (even)
    const int k16b   = kbeg >> 4;

    f16v acc[2][2];
#pragma unroll
    for (int m = 0; m < 2; ++m)
#pragma unroll
        for (int n = 0; n < 2; ++n) acc[m][n] = (f16v)0.f;

    const int srow = t >> 3;                // 0..31
    const int sg   = t & 7;                 // raw 16B granule
    const float* xg = X + (size_t)(m0 + srow) * DDIM + kbeg + sg * 8;

    const _Float16* bb = Bp + lane * 8;

    const _Float16 S5 = (_Float16)0.03125f;     // 2^-5
    const _Float16 S6 = (_Float16)0.015625f;    // 2^-6

#define AREAD(CUR, Q)                                                         \
    {                                                                         \
        _Pragma("unroll")                                                     \
        for (int m = 0; m < 2; ++m) {                                         \
            const int rr = m * 32 + (lane & 31);                              \
            const int gq = ((((Q) * 2 + (lane >> 5)) ^ (rr & 7))) * 8;        \
            a0[m] = *(const h8*)&sA[CUR][0][rr][gq];                          \
            a1[m] = *(const h8*)&sA[CUR][1][rr][gq];                          \
        }                                                                     \
    }

#define BLOADQ(RB, K16)                                                       \
    {                                                                         \
        _Pragma("unroll")                                                     \
        for (int p = 0; p < 2; ++p)                                           \
        _Pragma("unroll")                                                     \
        for (int n = 0; n < 2; ++n)                                           \
            RB[n][p] = *(const h8*)(bb +                                      \
                ((size_t)(p * 8 + w * 2 + n) * (2 * KT) + (K16)) * 512);      \
    }

#define LOADX2(R0, R1, PIECE, S)                                              \
    {                                                                         \
        const float* xp = xg + (size_t)(PIECE) * 32 * DDIM + (S) * 64;        \
        R0 = *(const float4*)(xp);                                            \
        R1 = *(const float4*)(xp + 4);                                        \
    }

#define CONVW(BUF, PIECE, R0, R1)                                             \
    {                                                                         \
        h8 p0, p1;                                                            \
        const float xv[8] = {R0.x, R0.y, R0.z, R0.w, R1.x, R1.y, R1.z, R1.w}; \
        _Pragma("unroll")                                                     \
        for (int q = 0; q < 8; ++q) {                                         \
            const _Float16 h0 = (_Float16)xv[q];                              \
            p0[q] = h0;                                                       \
            p1[q] = (_Float16)((xv[q] - (float)h0) * 2048.f);                 \
        }                                                                     \
        const int r  = srow + 32 * (PIECE);                                   \
        const int gq = (sg ^ (r & 7)) * 8;                                    \
        *(h8*)&sA[BUF][0][r][gq] = p0;                                        \
        *(h8*)&sA[BUF][1][r][gq] = p1;                                        \
    }

#define MFMAQ(RB)                                                             \
    {                                                                         \
        __builtin_amdgcn_s_setprio(1);                                        \
        _Pragma("unroll")                                                     \
        for (int m = 0; m < 2; ++m)                                           \
        _Pragma("unroll")                                                     \
        for (int n = 0; n < 2; ++n)                                           \
            acc[m][n] = __builtin_amdgcn_mfma_f32_32x32x16_f16(               \
                a0[m], RB[n][0], acc[m][n], 0, 0, 0);                         \
        _Pragma("unroll")                                                     \
        for (int n = 0; n < 2; ++n)                                           \
        _Pragma("unroll")                                                     \
        for (int q = 0; q < 8; ++q) RB[n][0][q] *= S5;                        \
        _Pragma("unroll")                                                     \
        for (int m = 0; m < 2; ++m)                                           \
        _Pragma("unroll")                                                     \
        for (int q = 0; q < 8; ++q) a1[m][q] *= S6;                           \
        _Pragma("unroll")                                                     \
        for (int m = 0; m < 2; ++m)                                           \
        _Pragma("unroll")                                                     \
        for (int n = 0; n < 2; ++n)                                           \
            acc[m][n] = __builtin_amdgcn_mfma_f32_32x32x16_f16(               \
                a1[m], RB[n][0], acc[m][n], 0, 0, 0);                         \
        _Pragma("unroll")                                                     \
        for (int m = 0; m < 2; ++m)                                           \
        _Pragma("unroll")                                                     \
        for (int q = 0; q < 8; ++q) a0[m][q] *= S5;                           \
        _Pragma("unroll")                                                     \
        for (int m = 0; m < 2; ++m)                                           \
        _Pragma("unroll")                                                     \
        for (int n = 0; n < 2; ++n)                                           \
            acc[m][n] = __builtin_amdgcn_mfma_f32_32x32x16_f16(               \
                a0[m], RB[n][1], acc[m][n], 0, 0, 0);                         \
        __builtin_amdgcn_s_setprio(0);                                        \
    }

#define PHASE(CUR, Q, RB, STG, BNX)                                           \
    {                                                                         \
        h8 a0[2], a1[2];                                                      \
        AREAD(CUR, Q);                                                        \
        STG;                                                                  \
        __builtin_amdgcn_s_barrier();                                         \
        asm volatile("s_waitcnt lgkmcnt(0)" ::: "memory");                    \
        __builtin_amdgcn_sched_barrier(0);                                    \
        MFMAQ(RB);                                                            \
        BNX;                                                                  \
        __builtin_amdgcn_s_barrier();                                         \
    }

#define STEP_BODY(S, CUR, L0, L1, L2, L3, W0, W1, W2, W3)                     \
    {                                                                         \
        const int kk = k16b + (S) * 4;                                        \
        const bool h1 = (S) + 1 < nsteps;                                     \
        const bool h2 = (S) + 2 < nsteps;                                     \
        PHASE(CUR, 0, bBuf0,                                                  \
              { if (h2) LOADX2(L0, L1, 0, (S) + 2); },                        \
              { BLOADQ(bBuf0, kk + 2); });                                    \
        PHASE(CUR, 1, bBuf1,                                                  \
              { if (h1) CONVW((CUR) ^ 1, 0, W0, W1); },                       \
              { BLOADQ(bBuf1, kk + 3); });                                    \
        PHASE(CUR, 2, bBuf0,                                                  \
              { if (h2) LOADX2(L2, L3, 1, (S) + 2); },                        \
              { if (h1) BLOADQ(bBuf0, kk + 4); });                            \
        PHASE(CUR, 3, bBuf1,                                                  \
              { if (h1) CONVW((CUR) ^ 1, 1, W2, W3); },                       \
              { if (h1) BLOADQ(bBuf1, kk + 5); });                            \
    }

    float4 xA0, xA1, xA2, xA3, xB0, xB1, xB2, xB3;
    h8 bBuf0[2][2], bBuf1[2][2];

    // ---- prologue ----
    LOADX2(xA0, xA1, 0, 0);
    LOADX2(xA2, xA3, 1, 0);
    BLOADQ(bBuf0, k16b + 0);
    BLOADQ(bBuf1, k16b + 1);
    CONVW(0, 0, xA0, xA1);
    CONVW(0, 1, xA2, xA3);
    if (nsteps > 1) { LOADX2(xB0, xB1, 0, 1); LOADX2(xB2, xB3, 1, 1); }
    asm volatile("s_waitcnt lgkmcnt(0)" ::: "memory");
    __builtin_amdgcn_s_barrier();

    for (int s = 0; s < nsteps; s += 2) {
        STEP_BODY(s,     0, xA0, xA1, xA2, xA3, xB0, xB1, xB2, xB3);
        STEP_BODY(s + 1, 1, xB0, xB1, xB2, xB3, xA0, xA1, xA2, xA3);
    }

    // epilogue: logit = acc/256
    const float s0 = 1.f / 256.f;
#pragma unroll
    for (int m = 0; m < 2; ++m)
#pragma unroll
        for (int n = 0; n < 2; ++n)
#pragma unroll
            for (int r = 0; r < 16; ++r) {
                const int row = (r & 3) + 8 * (r >> 2) + 4 * (lane >> 5);
                const int gr  = m0 + m * 32 + row;
                const int gc  = w * 64 + n * 32 + (lane & 31);
                P[((size_t)ks * TDIM + gr) * EDIM + gc] = acc[m][n][r] * s0;
            }

    // ---- fused routing: last-arriving block of this mb-group routes ----
    __threadfence();            // publish P writes (device scope)
    __syncthreads();            // all waves have published
    if (t == 0) {
        const int prev = atomicAdd(&cnt[mb], 1);
        isLast = (prev == SPLITK - 1) ? 1 : 0;
    }
    __syncthreads();
    if (!isLast) return;
    __threadfence();            // acquire: see all ks slices

    const float4 bv4 = *(const float4*)&Bias[lane * 4];
    const float bbv[4] = {bv4.x, bv4.y, bv4.z, bv4.w};
    const int g = lane >> 3;

    for (int i = 0; i < 16; ++i) {      // wave w routes tokens m0+w*16+i
        const int tok = m0 + w * 16 + i;
        float a[4] = {0.f, 0.f, 0.f, 0.f};
#pragma unroll
        for (int ksl = 0; ksl < SPLITK; ++ksl) {   // fixed order = bit-identical
            const float4 pv =
                *(const float4*)&P[((size_t)ksl * TDIM + tok) * EDIM + lane * 4];
            a[0] += pv.x; a[1] += pv.y; a[2] += pv.z; a[3] += pv.w;
        }
        float v[4], s[4];
#pragma unroll
        for (int jq = 0; jq < 4; ++jq) {
            v[jq] = 1.f / (1.f + expf(-a[jq]));
            s[jq] = v[jq] + bbv[jq];
        }
        float t1 = s[0], t2 = -FLT_MAX;
#pragma unroll
        for (int jq = 1; jq < 4; ++jq) {
            if (s[jq] > t1) { t2 = t1; t1 = s[jq]; }
            else if (s[jq] > t2) t2 = s[jq];
        }
#pragma unroll
        for (int d = 1; d < 8; d <<= 1) {
            float o1 = __shfl_xor(t1, d);
            float o2 = __shfl_xor(t2, d);
            float n1 = fmaxf(t1, o1);
            float n2 = fmaxf(fminf(t1, o1), fmaxf(t2, o2));
            t1 = n1; t2 = n2;
        }
        const float gsc = t1 + t2;
        float gs[8];
#pragma unroll
        for (int q = 0; q < 8; ++q) gs[q] = __shfl(gsc, q * 8);
        int gmask = 0;
#pragma unroll
        for (int it = 0; it < 4; ++it) {
            float bvv = -FLT_MAX; int bg = 0;
#pragma unroll
            for (int q = 0; q < 8; ++q) {
                const bool avail = ((gmask >> q) & 1) == 0;
                if (avail && gs[q] > bvv) { bvv = gs[q]; bg = q; }
            }
            gmask |= (1 << bg);
        }
        if (((gmask >> g) & 1) == 0) { s[0] = 0.f; s[1] = 0.f; s[2] = 0.f; s[3] = 0.f; }

        float wk[8]; int ik[8]; float wsum = 0.f;
#pragma unroll
        for (int it = 0; it < 8; ++it) {
            float bvv = s[0]; int bi = lane * 4; float bs = v[0];
#pragma unroll
            for (int jq = 1; jq < 4; ++jq)
                if (s[jq] > bvv) { bvv = s[jq]; bi = lane * 4 + jq; bs = v[jq]; }
#pragma unroll
            for (int d = 1; d < 64; d <<= 1) {
                float ov = __shfl_xor(bvv, d);
                int   oi = __shfl_xor(bi, d);
                float os = __shfl_xor(bs, d);
                if (ov > bvv || (ov == bvv && oi < bi)) { bvv = ov; bi = oi; bs = os; }
            }
            wk[it] = bs; ik[it] = bi; wsum += bs;
#pragma unroll
            for (int jq = 0; jq < 4; ++jq)
                if (bi == lane * 4 + jq) s[jq] = -FLT_MAX;
        }
        const float den = wsum + 1e-20f;
        if (lane == 0) {
#pragma unroll
            for (int q = 0; q < 8; ++q) {
                out[(size_t)tok * 8 + q] = wk[q] / den * 2.5f;
                out[(size_t)TDIM * 8 + (size_t)tok * 8 + q] = (float)ik[q];
            }
        }
    }
}

extern "C" void kernel_launch(void* const* d_in, const int* in_sizes, int n_in,
                              void* d_out, int out_size, void* d_ws, size_t ws_size,
                              hipStream_t stream)
{
    (void)in_sizes; (void)n_in; (void)out_size; (void)ws_size;
    const float* x    = (const float*)d_in[0];
    const float* kern = (const float*)d_in[1];
    const float* bias = (const float*)d_in[2];
    float* out = (float*)d_out;

    const size_t pBytes  = (size_t)SPLITK * TDIM * EDIM * 4;        // 33.5 MB
    const size_t bpBytes = (size_t)2 * 8 * KT * 2 * 512 * 2;        // 7.34 MB
    float* P = (float*)d_ws;
    _Float16* Bp = (_Float16*)((char*)d_ws + pBytes);
    int* cnt = (int*)((char*)d_ws + pBytes + bpBytes);              // 128 ints

    hipMemsetAsync(cnt, 0, 128 * sizeof(int), stream);
    convert_w<<<dim3(DDIM / 64, EDIM / 64), 256, 0, stream>>>(kern, Bp);
    gemm_mfma<<<(TDIM / 64) * SPLITK, 256, 0, stream>>>(
        x, Bp, P, bias, out, cnt);
}